// Round 1
// baseline (277.700 us; speedup 1.0000x reference)
//
#include <hip/hip_runtime.h>

#define BB 4096
#define TT 512
#define FIN 8
#define TC 64
#define NCHUNK (TT / TC)

__device__ __forceinline__ float sigmoidf_(float v) {
    return __builtin_amdgcn_rcpf(1.f + __expf(-v));
}

__launch_bounds__(256, 1)
__global__ void gru_fused(const float* __restrict__ x,
                          const float* __restrict__ W1, const float* __restrict__ Ur1,
                          const float* __restrict__ b1,
                          const float* __restrict__ W2, const float* __restrict__ Ur2,
                          const float* __restrict__ b2,
                          const float* __restrict__ Wd, const float* __restrict__ bd,
                          const float* __restrict__ Wo, const float* __restrict__ bo,
                          float* __restrict__ out)
{
    // per-block: 16 batch rows; all LDS producer/consumer pairs are wave-internal
    __shared__ float xs[16][TC * FIN + 8];   // +8 pad: group addrs land on distinct banks
    __shared__ float h1x[16][8];
    __shared__ float h2x[16][20];            // stride 20: groups at banks {0,20,8,28}
    __shared__ float outs[16][TC];

    const int tid  = threadIdx.x;
    const int wave = tid >> 6;
    const int lane = tid & 63;
    const int g    = (lane >> 4) & 3;
    const int j    = lane & 15;      // GRU2 / dense unit owned by this lane
    const int u1   = j & 7;          // GRU1 unit (lanes 8..15 duplicate 0..7)
    const int bl   = wave * 4 + g;   // batch row within block, 0..15

    // ---- weights into registers (per-lane columns; static indices only) ----
    float w1z[8], w1r[8], w1h[8], q1z[8], q1r[8], q1h[8];
#pragma unroll
    for (int f = 0; f < 8; ++f) {
        w1z[f] = W1[f * 24 + u1];
        w1r[f] = W1[f * 24 + 8 + u1];
        w1h[f] = W1[f * 24 + 16 + u1];
        q1z[f] = Ur1[f * 24 + u1];
        q1r[f] = Ur1[f * 24 + 8 + u1];
        q1h[f] = Ur1[f * 24 + 16 + u1];
    }
    const float bz1 = b1[u1],      brr1 = b1[8 + u1],  bh1 = b1[16 + u1];
    const float cz1 = b1[24 + u1], cr1  = b1[32 + u1], ch1 = b1[40 + u1];

    float w2z[8], w2r[8], w2h[8];
#pragma unroll
    for (int f = 0; f < 8; ++f) {
        w2z[f] = W2[f * 48 + j];
        w2r[f] = W2[f * 48 + 16 + j];
        w2h[f] = W2[f * 48 + 32 + j];
    }
    float q2z[16], q2r[16], q2h[16];
#pragma unroll
    for (int k = 0; k < 16; ++k) {
        q2z[k] = Ur2[k * 48 + j];
        q2r[k] = Ur2[k * 48 + 16 + j];
        q2h[k] = Ur2[k * 48 + 32 + j];
    }
    const float bz2 = b2[j],      brr2 = b2[16 + j], bh2 = b2[32 + j];
    const float cz2 = b2[48 + j], cr2  = b2[64 + j], ch2 = b2[80 + j];

    float wdc[16];
#pragma unroll
    for (int k = 0; k < 16; ++k) wdc[k] = Wd[k * 16 + j];
    const float bdj = bd[j];
    const float woj = Wo[j];
    const float boo = bo[0];

    // state: own unit value as scalar (no runtime indexing -> stays in VGPRs)
    float h1own = 0.f, h2own = 0.f;
    float h1[8], h2[16];
#pragma unroll
    for (int k = 0; k < 8; ++k) h1[k] = 0.f;
#pragma unroll
    for (int k = 0; k < 16; ++k) h2[k] = 0.f;

    // staging mapping: thread (row, q); row == this wave's own batch rows
    const int row = tid >> 4;
    const int q   = tid & 15;
    const float* xrow = x + ((size_t)(blockIdx.x * 16 + row) * TT) * FIN;

    for (int c = 0; c < NCHUNK; ++c) {
        // ---- stage 64 timesteps of x, coalesced float4 ----
        const float4* src = (const float4*)(xrow + c * TC * FIN);
#pragma unroll
        for (int k = 0; k < 8; ++k) {
            float4 v = src[q + 16 * k];
            *(float4*)&xs[row][(q + 16 * k) * 4] = v;
        }
        __builtin_amdgcn_wave_barrier();

        float4 xa = *(const float4*)&xs[bl][0];
        float4 xb = *(const float4*)&xs[bl][4];

        for (int tl = 0; tl < TC; ++tl) {
            const float xv[8] = {xa.x, xa.y, xa.z, xa.w, xb.x, xb.y, xb.z, xb.w};
            if (tl + 1 < TC) {  // prefetch next timestep's x (recurrence-independent)
                xa = *(const float4*)&xs[bl][(tl + 1) * 8];
                xb = *(const float4*)&xs[bl][(tl + 1) * 8 + 4];
            }

            // ---- GRU1 (unit u1) ----
            float gz = bz1, gr = brr1, gh = bh1;
            float iz = cz1, ir = cr1, ih = ch1;
#pragma unroll
            for (int f = 0; f < 8; ++f) {
                gz = fmaf(xv[f], w1z[f], gz);
                gr = fmaf(xv[f], w1r[f], gr);
                gh = fmaf(xv[f], w1h[f], gh);
                iz = fmaf(h1[f], q1z[f], iz);
                ir = fmaf(h1[f], q1r[f], ir);
                ih = fmaf(h1[f], q1h[f], ih);
            }
            const float z1  = sigmoidf_(gz + iz);
            const float r1  = sigmoidf_(gr + ir);
            const float hh1 = fmaxf(fmaf(r1, ih, gh), 0.f);
            h1own = z1 * h1own + (1.f - z1) * hh1;

            h1x[bl][u1] = h1own;             // lanes j and j+8 write same value: benign
            __builtin_amdgcn_wave_barrier();
            *(float4*)&h1[0] = *(const float4*)&h1x[bl][0];
            *(float4*)&h1[4] = *(const float4*)&h1x[bl][4];

            // ---- GRU2 (unit j) ----
            float gz2 = bz2, gr2 = brr2, gh2 = bh2;
#pragma unroll
            for (int f = 0; f < 8; ++f) {
                gz2 = fmaf(h1[f], w2z[f], gz2);
                gr2 = fmaf(h1[f], w2r[f], gr2);
                gh2 = fmaf(h1[f], w2h[f], gh2);
            }
            float iz2 = cz2, ir2 = cr2, ih2 = ch2;
#pragma unroll
            for (int k = 0; k < 16; ++k) {
                iz2 = fmaf(h2[k], q2z[k], iz2);
                ir2 = fmaf(h2[k], q2r[k], ir2);
                ih2 = fmaf(h2[k], q2h[k], ih2);
            }
            const float z2  = sigmoidf_(gz2 + iz2);
            const float r2  = sigmoidf_(gr2 + ir2);
            const float hh2 = fmaxf(fmaf(r2, ih2, gh2), 0.f);
            h2own = z2 * h2own + (1.f - z2) * hh2;

            h2x[bl][j] = h2own;
            __builtin_amdgcn_wave_barrier();
#pragma unroll
            for (int k = 0; k < 4; ++k)
                *(float4*)&h2[k * 4] = *(const float4*)&h2x[bl][k * 4];

            // ---- dense + head ----
            float acc = bdj;
#pragma unroll
            for (int k = 0; k < 16; ++k) acc = fmaf(h2[k], wdc[k], acc);
            float contrib = fmaxf(acc, 0.f) * woj;
            contrib += __shfl_xor(contrib, 1);
            contrib += __shfl_xor(contrib, 2);
            contrib += __shfl_xor(contrib, 4);
            contrib += __shfl_xor(contrib, 8);
            if (j == 0) outs[bl][tl] = contrib + boo;
        }
        __builtin_amdgcn_wave_barrier();

        // ---- dump out chunk, coalesced float4 (same-wave rows) ----
        float4 ov = *(const float4*)&outs[row][q * 4];
        *(float4*)&out[((size_t)(blockIdx.x * 16 + row)) * TT + c * TC + q * 4] = ov;
    }
}

extern "C" void kernel_launch(void* const* d_in, const int* in_sizes, int n_in,
                              void* d_out, int out_size, void* d_ws, size_t ws_size,
                              hipStream_t stream) {
    const float* x   = (const float*)d_in[0];
    const float* W1  = (const float*)d_in[1];
    const float* Ur1 = (const float*)d_in[2];
    const float* b1  = (const float*)d_in[3];
    const float* W2  = (const float*)d_in[4];
    const float* Ur2 = (const float*)d_in[5];
    const float* b2  = (const float*)d_in[6];
    const float* Wd  = (const float*)d_in[7];
    const float* bd  = (const float*)d_in[8];
    const float* Wo  = (const float*)d_in[9];
    const float* bo  = (const float*)d_in[10];
    float* out = (float*)d_out;

    dim3 grid(BB / 16);   // 256 blocks
    dim3 block(256);      // 4 waves, 16 batch rows/block, 16 lanes/batch
    gru_fused<<<grid, block, 0, stream>>>(x, W1, Ur1, b1, W2, Ur2, b2,
                                          Wd, bd, Wo, bo, out);
}

// Round 2
// 236.768 us; speedup vs baseline: 1.1729x; 1.1729x over previous
//
#include <hip/hip_runtime.h>

#define TT 512
#define FIN 8
#define CH 32
#define NCH 16            // 512 / 32 chunks
#define NPH (NCH + 2)     // pipeline phases (fill depth 3)
#define ROWS 8            // batch rows per block

__device__ __forceinline__ float sigmoidf_(float v) {
    return __builtin_amdgcn_rcpf(1.f + __expf(-v));
}

__launch_bounds__(256, 2)
__global__ void gru_pipe(const float* __restrict__ x,
                         const float* __restrict__ W1, const float* __restrict__ Ur1,
                         const float* __restrict__ b1,
                         const float* __restrict__ W2, const float* __restrict__ Ur2,
                         const float* __restrict__ b2,
                         const float* __restrict__ Wd, const float* __restrict__ bd,
                         const float* __restrict__ Wo, const float* __restrict__ bo,
                         float* __restrict__ out)
{
    // double-buffered per-chunk histories; strides padded: 264%32=8, 520%32=8
    // -> worst case 2-way bank aliasing (free), rows 16B-aligned (1056B/2080B)
    __shared__ __align__(16) float h1h[2][ROWS][CH * 8 + 8];
    __shared__ __align__(16) float h2h[2][ROWS][CH * 16 + 8];

    const int tid = threadIdx.x;
    const int w = tid >> 6;          // wave role: 0=GRU1, 1..2=GRU2, 3=dense
    const int lane = tid & 63;
    const int rowbase = blockIdx.x * ROWS;

    if (w == 0) {
        // ================= GRU1 wave: 8 lanes per row, 8 rows =================
        const int row8 = lane >> 3;
        const int u1   = lane & 7;
        const float* xrow = x + (size_t)(rowbase + row8) * TT * FIN;

        float w1z[8], w1r[8], w1h[8], q1z[8], q1r[8], q1h[8];
#pragma unroll
        for (int f = 0; f < 8; ++f) {
            w1z[f] = W1[f * 24 + u1];  w1r[f] = W1[f * 24 + 8 + u1];  w1h[f] = W1[f * 24 + 16 + u1];
            q1z[f] = Ur1[f * 24 + u1]; q1r[f] = Ur1[f * 24 + 8 + u1]; q1h[f] = Ur1[f * 24 + 16 + u1];
        }
        const float bz1 = b1[u1],      br1 = b1[8 + u1],  bh1 = b1[16 + u1];
        const float cz1 = b1[24 + u1], cr1 = b1[32 + u1], ch1 = b1[40 + u1];

        float h1v[8];
#pragma unroll
        for (int k = 0; k < 8; ++k) h1v[k] = 0.f;
        float h1own = 0.f;

        for (int p = 0; p < NPH; ++p) {
            if (p < NCH) {
                const int buf = p & 1;
                const int t0  = p * CH;
                float4 xq[4][2];                       // 3-deep x prefetch queue
#pragma unroll
                for (int k = 0; k < 3; ++k) {
                    const float4* xp = (const float4*)(xrow + (size_t)(t0 + k) * FIN);
                    xq[k][0] = xp[0]; xq[k][1] = xp[1];
                }
                float pgz, pgr, pgh;                   // x-side gates for step s
                {
                    const float xv[8] = {xq[0][0].x, xq[0][0].y, xq[0][0].z, xq[0][0].w,
                                         xq[0][1].x, xq[0][1].y, xq[0][1].z, xq[0][1].w};
                    pgz = bz1; pgr = br1; pgh = bh1;
#pragma unroll
                    for (int f = 0; f < 8; ++f) {
                        pgz = fmaf(xv[f], w1z[f], pgz);
                        pgr = fmaf(xv[f], w1r[f], pgr);
                        pgh = fmaf(xv[f], w1h[f], pgh);
                    }
                }
#pragma unroll 4
                for (int s = 0; s < CH; ++s) {
                    float iz = cz1, ir = cr1, ih = ch1;
#pragma unroll
                    for (int f = 0; f < 8; ++f) {
                        iz = fmaf(h1v[f], q1z[f], iz);
                        ir = fmaf(h1v[f], q1r[f], ir);
                        ih = fmaf(h1v[f], q1h[f], ih);
                    }
                    const float z1  = sigmoidf_(pgz + iz);
                    const float r1  = sigmoidf_(pgr + ir);
                    const float hh1 = fmaxf(fmaf(r1, ih, pgh), 0.f);
                    h1own = z1 * h1own + (1.f - z1) * hh1;
                    h1h[buf][row8][s * 8 + u1] = h1own;
                    {   // issue x load for step s+3 (wrapped tail loads are dead values)
                        const int tf = (t0 + s + 3) & (TT - 1);
                        const float4* xp = (const float4*)(xrow + (size_t)tf * FIN);
                        xq[(s + 3) & 3][0] = xp[0]; xq[(s + 3) & 3][1] = xp[1];
                    }
                    {   // x-side gates for s+1 — covers the h1h read latency below
                        const float4 a = xq[(s + 1) & 3][0], bq = xq[(s + 1) & 3][1];
                        const float xv[8] = {a.x, a.y, a.z, a.w, bq.x, bq.y, bq.z, bq.w};
                        pgz = bz1; pgr = br1; pgh = bh1;
#pragma unroll
                        for (int f = 0; f < 8; ++f) {
                            pgz = fmaf(xv[f], w1z[f], pgz);
                            pgr = fmaf(xv[f], w1r[f], pgr);
                            pgh = fmaf(xv[f], w1h[f], pgh);
                        }
                    }
                    __builtin_amdgcn_wave_barrier();
                    *(float4*)&h1v[0] = *(const float4*)&h1h[buf][row8][s * 8];
                    *(float4*)&h1v[4] = *(const float4*)&h1h[buf][row8][s * 8 + 4];
                }
            }
            __syncthreads();
        }
    } else if (w <= 2) {
        // ================= GRU2 waves: 16 lanes per row, 4 rows each ==========
        const int rloc = (w - 1) * 4 + (lane >> 4);
        const int j    = lane & 15;

        float w2z[8], w2r[8], w2h[8];
#pragma unroll
        for (int f = 0; f < 8; ++f) {
            w2z[f] = W2[f * 48 + j]; w2r[f] = W2[f * 48 + 16 + j]; w2h[f] = W2[f * 48 + 32 + j];
        }
        float q2z[16], q2r[16], q2h[16];
#pragma unroll
        for (int k = 0; k < 16; ++k) {
            q2z[k] = Ur2[k * 48 + j]; q2r[k] = Ur2[k * 48 + 16 + j]; q2h[k] = Ur2[k * 48 + 32 + j];
        }
        const float bz2 = b2[j],      br2 = b2[16 + j], bh2 = b2[32 + j];
        const float cz2 = b2[48 + j], cr2 = b2[64 + j], ch2 = b2[80 + j];

        float h2v[16];
#pragma unroll
        for (int k = 0; k < 16; ++k) h2v[k] = 0.f;
        float h2own = 0.f;

        for (int p = 0; p < NPH; ++p) {
            if (p >= 1 && p <= NCH) {
                const int cd  = p - 1;
                const int buf = cd & 1;
                float h1q[2][8];                       // h1(s+1), h1(s+2) rotation
                float pgz, pgr, pgh;
                {
                    *(float4*)&h1q[0][0] = *(const float4*)&h1h[buf][rloc][0];
                    *(float4*)&h1q[0][4] = *(const float4*)&h1h[buf][rloc][4];
                    *(float4*)&h1q[1][0] = *(const float4*)&h1h[buf][rloc][8];
                    *(float4*)&h1q[1][4] = *(const float4*)&h1h[buf][rloc][12];
                    pgz = bz2; pgr = br2; pgh = bh2;
#pragma unroll
                    for (int f = 0; f < 8; ++f) {
                        pgz = fmaf(h1q[0][f], w2z[f], pgz);
                        pgr = fmaf(h1q[0][f], w2r[f], pgr);
                        pgh = fmaf(h1q[0][f], w2h[f], pgh);
                    }
                }
#pragma unroll 4
                for (int s = 0; s < CH; ++s) {
                    float iz = cz2, ir = cr2, ih = ch2;
#pragma unroll
                    for (int k = 0; k < 16; ++k) {
                        iz = fmaf(h2v[k], q2z[k], iz);
                        ir = fmaf(h2v[k], q2r[k], ir);
                        ih = fmaf(h2v[k], q2h[k], ih);
                    }
                    const float z2  = sigmoidf_(pgz + iz);
                    const float r2  = sigmoidf_(pgr + ir);
                    const float hh2 = fmaxf(fmaf(r2, ih, pgh), 0.f);
                    h2own = z2 * h2own + (1.f - z2) * hh2;
                    h2h[buf][rloc][s * 16 + j] = h2own;
                    {   // prefetch h1(s+2) into slot (s+2)&1 == s&1 (wrapped tail = dead)
                        const int sn = (s + 2) & (CH - 1);
                        *(float4*)&h1q[s & 1][0] = *(const float4*)&h1h[buf][rloc][sn * 8];
                        *(float4*)&h1q[s & 1][4] = *(const float4*)&h1h[buf][rloc][sn * 8 + 4];
                    }
                    {   // x-side gates for s+1 from h1(s+1) — covers h2h read below
                        pgz = bz2; pgr = br2; pgh = bh2;
#pragma unroll
                        for (int f = 0; f < 8; ++f) {
                            pgz = fmaf(h1q[(s + 1) & 1][f], w2z[f], pgz);
                            pgr = fmaf(h1q[(s + 1) & 1][f], w2r[f], pgr);
                            pgh = fmaf(h1q[(s + 1) & 1][f], w2h[f], pgh);
                        }
                    }
                    __builtin_amdgcn_wave_barrier();
#pragma unroll
                    for (int k = 0; k < 4; ++k)
                        *(float4*)&h2v[k * 4] = *(const float4*)&h2h[buf][rloc][s * 16 + k * 4];
                }
            }
            __syncthreads();
        }
    } else {
        // ================= dense/head wave: lane=(r4, j), 2 rows per lane =====
        const int r4 = lane >> 4;     // 0..3
        const int j  = lane & 15;
        float wdc[16];
#pragma unroll
        for (int k = 0; k < 16; ++k) wdc[k] = Wd[k * 16 + j];
        const float bdj = bd[j], woj = Wo[j], boo = bo[0];

        for (int p = 0; p < NPH; ++p) {
            if (p >= 2) {
                const int cd  = p - 2;
                const int buf = cd & 1;
                const int t0  = cd * CH;
#pragma unroll 2
                for (int s = 0; s < CH; ++s) {
#pragma unroll
                    for (int rr = r4; rr < ROWS; rr += 4) {
                        float hv[16];
#pragma unroll
                        for (int k = 0; k < 4; ++k)
                            *(float4*)&hv[k * 4] = *(const float4*)&h2h[buf][rr][s * 16 + k * 4];
                        float acc = bdj;
#pragma unroll
                        for (int k = 0; k < 16; ++k) acc = fmaf(hv[k], wdc[k], acc);
                        float hd = fmaxf(acc, 0.f) * woj;
                        hd += __shfl_xor(hd, 1);
                        hd += __shfl_xor(hd, 2);
                        hd += __shfl_xor(hd, 4);
                        hd += __shfl_xor(hd, 8);
                        if (j == 0) out[(size_t)(rowbase + rr) * TT + t0 + s] = hd + boo;
                    }
                }
            }
            __syncthreads();
        }
    }
}

extern "C" void kernel_launch(void* const* d_in, const int* in_sizes, int n_in,
                              void* d_out, int out_size, void* d_ws, size_t ws_size,
                              hipStream_t stream) {
    const float* x   = (const float*)d_in[0];
    const float* W1  = (const float*)d_in[1];
    const float* Ur1 = (const float*)d_in[2];
    const float* b1  = (const float*)d_in[3];
    const float* W2  = (const float*)d_in[4];
    const float* Ur2 = (const float*)d_in[5];
    const float* b2  = (const float*)d_in[6];
    const float* Wd  = (const float*)d_in[7];
    const float* bd  = (const float*)d_in[8];
    const float* Wo  = (const float*)d_in[9];
    const float* bo  = (const float*)d_in[10];
    float* out = (float*)d_out;

    dim3 grid(4096 / ROWS);   // 512 blocks -> 2 blocks/CU -> 2 waves/SIMD
    dim3 block(256);          // 4 waves: GRU1, GRU2 x2, dense
    gru_pipe<<<grid, block, 0, stream>>>(x, W1, Ur1, b1, W2, Ur2, b2,
                                         Wd, bd, Wo, bo, out);
}